// Round 7
// baseline (39.209 us; speedup 1.0000x reference)
//
#include <hip/hip_runtime.h>
#include <hip/hip_fp16.h>
#include <math.h>

#define NFIELDS 50
#define EMBD 64
#define NPAIRS 1225
#define NTILEPAD 40
#define NPAD (NTILEPAD * 32)      // 1280
#define NTHREADS 256
#define NWAVES 4
#define NITER (NTILEPAD / NWAVES) // 10
#define QPT (NPAD / NTHREADS)     // 5
#define NFPAD 51
#define CHSTR (NFPAD * 8)         // u16 units per chunk slab = 408

typedef _Float16 f16x8 __attribute__((ext_vector_type(8)));
typedef _Float16 f16x2 __attribute__((ext_vector_type(2)));
typedef __fp16   fp16x2 __attribute__((ext_vector_type(2)));
typedef float f32x16 __attribute__((ext_vector_type(16)));

union F16x8U { f16x8 v; f16x2 h2[4]; unsigned int u[4]; uint4 q; };
union U32F { unsigned int u; f16x2 h; fp16x2 g; };

__device__ __forceinline__ f16x2 pkrtz(float a, float b) {
    U32F t; t.g = __builtin_amdgcn_cvt_pkrtz(a, b);
    return t.h;
}

__device__ __forceinline__ float dot2acc(f16x2 a, f16x2 b, float c) {
#if __has_builtin(__builtin_amdgcn_fdot2)
    return __builtin_amdgcn_fdot2(a, b, c, false);
#else
    return c + (float)a[0] * (float)b[0] + (float)a[1] * (float)b[1];
#endif
}

#define MNEG (-1e30f)

__launch_bounds__(NTHREADS, 4)
__global__ void afm_kernel(const int* __restrict__ features,
                           const float* __restrict__ emb_table,
                           const float* __restrict__ coeff_table,
                           const float* __restrict__ bias,
                           const float* __restrict__ att_w,
                           const float* __restrict__ att_b,
                           const float* __restrict__ pvec,
                           const float* __restrict__ wvec,
                           float* __restrict__ out)
{
    // chunk-major: chunk q = h*4 + c holds logical dims d = c*16 + h*8 + [0..8)
    __shared__ __align__(16) unsigned short emb3[8][NFPAD][8];
    __shared__ unsigned short pair_s[NPAD];    // (i<<8)|j
    __shared__ int   feat_s[NFIELDS];
    __shared__ float red_m[NWAVES], red_s[NWAVES], red_st[NWAVES];
    __shared__ float red_csum;

    const int b    = blockIdx.x;
    const int tid  = threadIdx.x;
    const int lane = tid & 63;
    const int wid  = tid >> 6;
    const int col  = lane & 31;   // MFMA output col = PAIR within tile
    const int h    = lane >> 5;   // k-group half
    const int h4   = h * 4;

    // ---- phase 0a: features, pair table (closed form), coeff+bias reduce ----
    int myfeat = 0;
    if (tid < NFIELDS) {
        myfeat = features[b * NFIELDS + tid];
        feat_s[tid] = myfeat;
    }

    #pragma unroll
    for (int k = 0; k < QPT; ++k) {
        const int q = tid * QPT + k;
        int i = 0, j = 1;
        if (q < NPAIRS) {
            const float s = sqrtf((float)(9801 - 8 * q));
            i = (int)((99.0f - s) * 0.5f);
            const int off = i * NFIELDS - ((i * (i + 1)) >> 1);
            j = i + 1 + (q - off);
        }
        pair_s[q] = (unsigned short)((i << 8) | j);
    }

    if (wid == 0) {   // coeff sum + bias via wave shuffle reduce
        float cacc = 0.f;
        if (tid < NFIELDS)       cacc = coeff_table[myfeat];
        else if (tid == NFIELDS) cacc = bias[0];
        #pragma unroll
        for (int m = 1; m < 64; m <<= 1) cacc += __shfl_xor(cacc, m, 64);
        if (tid == 0) red_csum = cacc;
    }

    // ---- per-lane register weights (A-operand = att_w, stationary) ----
    f16x8 afragW[4];
    f16x2 w2[16];
    #pragma unroll
    for (int c = 0; c < 4; ++c) {
        const int d0 = c * 16 + h * 8;
        const float4 wa0 = *reinterpret_cast<const float4*>(&att_w[col * EMBD + d0]);
        const float4 wa1 = *reinterpret_cast<const float4*>(&att_w[col * EMBD + d0 + 4]);
        F16x8U bf;
        bf.v[0] = (_Float16)wa0.x; bf.v[1] = (_Float16)wa0.y;
        bf.v[2] = (_Float16)wa0.z; bf.v[3] = (_Float16)wa0.w;
        bf.v[4] = (_Float16)wa1.x; bf.v[5] = (_Float16)wa1.y;
        bf.v[6] = (_Float16)wa1.z; bf.v[7] = (_Float16)wa1.w;
        afragW[c] = bf.v;
        const float4 wv0 = *reinterpret_cast<const float4*>(&wvec[d0]);
        const float4 wv1 = *reinterpret_cast<const float4*>(&wvec[d0 + 4]);
        f16x2 t0; t0[0] = (_Float16)wv0.x; t0[1] = (_Float16)wv0.y; w2[c * 4 + 0] = t0;
        f16x2 t1; t1[0] = (_Float16)wv0.z; t1[1] = (_Float16)wv0.w; w2[c * 4 + 1] = t1;
        f16x2 t2; t2[0] = (_Float16)wv1.x; t2[1] = (_Float16)wv1.y; w2[c * 4 + 2] = t2;
        f16x2 t3; t3[0] = (_Float16)wv1.z; t3[1] = (_Float16)wv1.w; w2[c * 4 + 3] = t3;
    }
    // per-reg output-row constants: row(reg) = (reg&3) + 8*(reg>>2) + 4*h
    float attb_r[16];
    f16x2 p16[8];
    #pragma unroll
    for (int reg = 0; reg < 16; ++reg) {
        const int r = (reg & 3) + 8 * (reg >> 2) + 4 * h;
        attb_r[reg] = att_b[r];
    }
    #pragma unroll
    for (int q = 0; q < 8; ++q) {
        const int r0 = ((2 * q) & 3) + 8 * ((2 * q) >> 2) + 4 * h;
        const int r1 = ((2 * q + 1) & 3) + 8 * ((2 * q + 1) >> 2) + 4 * h;
        f16x2 pp; pp[0] = (_Float16)pvec[r0]; pp[1] = (_Float16)pvec[r1];
        p16[q] = pp;
    }
    __syncthreads();

    // ---- phase 0b: gather embeddings -> f16 chunk-major LDS ----
    for (int idx = tid; idx < NFIELDS * 16; idx += NTHREADS) {
        const int f  = idx >> 4;
        const int d0 = (idx & 15) * 4;            // logical dim start
        const float4 v = *reinterpret_cast<const float4*>(
            &emb_table[(size_t)feat_s[f] * EMBD + d0]);
        const int c  = d0 >> 4;
        const int hh = (d0 >> 3) & 1;
        const int e0 = d0 & 7;                    // 0 or 4
        U32F t0, t1;
        t0.h[0] = (_Float16)v.x; t0.h[1] = (_Float16)v.y;
        t1.h[0] = (_Float16)v.z; t1.h[1] = (_Float16)v.w;
        uint2 pk; pk.x = t0.u; pk.y = t1.u;
        *reinterpret_cast<uint2*>(&emb3[hh * 4 + c][f][e0]) = pk;
    }
    __syncthreads();

    // ---- main: rolled loop, explicit 1-deep LDS prefetch, online softmax ----
    const unsigned short* const ebase = &emb3[0][0][0] + h4 * CHSTR;

    float m_run = MNEG, s_run = 0.f, st_run = 0.f;

    uint4 ai_c[4], aj_c[4];
    int pidx_cur = wid * 32 + col;
    {
        const unsigned int ij = pair_s[pidx_cur];
        const unsigned short* pi = ebase + (ij >> 8) * 8;
        const unsigned short* pj = ebase + (ij & 255) * 8;
        #pragma unroll
        for (int c = 0; c < 4; ++c) {
            ai_c[c] = *reinterpret_cast<const uint4*>(pi + c * CHSTR);
            aj_c[c] = *reinterpret_cast<const uint4*>(pj + c * CHSTR);
        }
    }

    #pragma unroll 1
    for (int tt = 0; tt < NITER; ++tt) {
        // ---- prefetch tile t+1 (wraps to tile wid at tt=9; harmless) ----
        const int ttn   = (tt + 1 < NITER) ? (tt + 1) : 0;
        const int pidx_n = (wid + ttn * NWAVES) * 32 + col;
        uint4 ai_n[4], aj_n[4];
        {
            const unsigned int ijn = pair_s[pidx_n];
            const unsigned short* pin = ebase + (ijn >> 8) * 8;
            const unsigned short* pjn = ebase + (ijn & 255) * 8;
            #pragma unroll
            for (int c = 0; c < 4; ++c) {
                ai_n[c] = *reinterpret_cast<const uint4*>(pin + c * CHSTR);
                aj_n[c] = *reinterpret_cast<const uint4*>(pjn + c * CHSTR);
            }
        }

        // ---- compute on current tile ----
        f32x16 acc;
        #pragma unroll
        for (int reg = 0; reg < 16; ++reg) acc[reg] = attb_r[reg];

        float t_half = 0.f;
        #pragma unroll
        for (int c = 0; c < 4; ++c) {
            F16x8U ai, aj;
            ai.q = ai_c[c]; aj.q = aj_c[c];
            const f16x2 x0 = ai.h2[0] * aj.h2[0];   // v_pk_mul_f16
            const f16x2 x1 = ai.h2[1] * aj.h2[1];
            const f16x2 x2 = ai.h2[2] * aj.h2[2];
            const f16x2 x3 = ai.h2[3] * aj.h2[3];
            t_half = dot2acc(x0, w2[c * 4 + 0], t_half);
            t_half = dot2acc(x1, w2[c * 4 + 1], t_half);
            t_half = dot2acc(x2, w2[c * 4 + 2], t_half);
            t_half = dot2acc(x3, w2[c * 4 + 3], t_half);
            F16x8U bf;
            bf.h2[0] = x0; bf.h2[1] = x1; bf.h2[2] = x2; bf.h2[3] = x3;
            acc = __builtin_amdgcn_mfma_f32_32x32x16_f16(afragW[c], bf.v, acc, 0, 0, 0);
        }

        // ---- epilogue: relu pairs packed to f16, dot2 with packed p ----
        float sp = 0.f;
        #pragma unroll
        for (int q = 0; q < 8; ++q) {
            const float r0 = fmaxf(acc[2 * q],     0.f);
            const float r1 = fmaxf(acc[2 * q + 1], 0.f);
            const f16x2 rr = pkrtz(r0, r1);
            sp = dot2acc(rr, p16[q], sp);
        }

        // one packed cross-half exchange for (sp, t_half)
        U32F pkd; pkd.h = pkrtz(sp, t_half);
        U32F oth; oth.u = (unsigned int)__shfl_xor((int)pkd.u, 32, 64);
        const float sc = sp + (float)oth.h[0];
        const float tf = t_half + (float)oth.h[1];

        // ---- online softmax update (h duplicates cancel in ST/S) ----
        const bool valid = (pidx_cur < NPAIRS);
        const float scm = valid ? sc : MNEG;
        const float mn  = fmaxf(m_run, scm);
        const float scale = __expf(m_run - mn);
        const float e     = valid ? __expf(sc - mn) : 0.f;
        s_run  = s_run  * scale + e;
        st_run = st_run * scale + e * tf;
        m_run  = mn;

        // ---- rotate prefetch buffers ----
        #pragma unroll
        for (int c = 0; c < 4; ++c) { ai_c[c] = ai_n[c]; aj_c[c] = aj_n[c]; }
        pidx_cur = pidx_n;
    }

    // ---- merge online states: 64-lane butterfly, then cross-wave via LDS ----
    #pragma unroll
    for (int m = 1; m < 64; m <<= 1) {
        const float m2  = __shfl_xor(m_run, m, 64);
        const float s2  = __shfl_xor(s_run, m, 64);
        const float st2 = __shfl_xor(st_run, m, 64);
        const float mn  = fmaxf(m_run, m2);
        const float ea  = __expf(m_run - mn);
        const float eb  = __expf(m2 - mn);
        s_run  = s_run * ea + s2 * eb;
        st_run = st_run * ea + st2 * eb;
        m_run  = mn;
    }
    if (lane == 0) { red_m[wid] = m_run; red_s[wid] = s_run; red_st[wid] = st_run; }
    __syncthreads();

    if (tid == 0) {
        float M = red_m[0], S = red_s[0], ST = red_st[0];
        #pragma unroll
        for (int wq = 1; wq < NWAVES; ++wq) {
            const float mn = fmaxf(M, red_m[wq]);
            const float ea = __expf(M - mn);
            const float eb = __expf(red_m[wq] - mn);
            S  = S * ea + red_s[wq] * eb;
            ST = ST * ea + red_st[wq] * eb;
            M  = mn;
        }
        out[b] = ST / S + red_csum;
    }
}

extern "C" void kernel_launch(void* const* d_in, const int* in_sizes, int n_in,
                              void* d_out, int out_size, void* d_ws, size_t ws_size,
                              hipStream_t stream) {
    const int*   features    = (const int*)d_in[0];
    const float* emb_table   = (const float*)d_in[1];
    const float* coeff_table = (const float*)d_in[2];
    const float* bias        = (const float*)d_in[3];
    const float* att_w       = (const float*)d_in[4];
    const float* att_b       = (const float*)d_in[5];
    const float* pvec        = (const float*)d_in[6];
    const float* wvec        = (const float*)d_in[7];
    float* out = (float*)d_out;

    const int batch = in_sizes[0] / NFIELDS;   // 2048
    afm_kernel<<<batch, NTHREADS, 0, stream>>>(
        features, emb_table, coeff_table, bias, att_w, att_b, pvec, wvec, out);
}

// Round 8
// 36.924 us; speedup vs baseline: 1.0619x; 1.0619x over previous
//
#include <hip/hip_runtime.h>
#include <hip/hip_fp16.h>
#include <math.h>

#define NFIELDS 50
#define EMBD 64
#define NPAIRS 1225
#define NTILES 39          // ceil(1225/32)
#define NFPAD 51
#define CHSTR (NFPAD * 8)  // u16 units per chunk slab = 408
#define MNEG (-1e30f)

typedef _Float16 f16x8 __attribute__((ext_vector_type(8)));
typedef _Float16 f16x2 __attribute__((ext_vector_type(2)));
typedef __fp16   fp16x2 __attribute__((ext_vector_type(2)));
typedef float f32x16 __attribute__((ext_vector_type(16)));

union F16x8U { f16x8 v; f16x2 h2[4]; unsigned int u[4]; uint4 q; };
union U32F { unsigned int u; f16x2 h; fp16x2 g; };

__device__ __forceinline__ f16x2 pkrtz(float a, float b) {
    U32F t; t.g = __builtin_amdgcn_cvt_pkrtz(a, b);
    return t.h;
}

__device__ __forceinline__ float dot2acc(f16x2 a, f16x2 b, float c) {
#if __has_builtin(__builtin_amdgcn_fdot2)
    return __builtin_amdgcn_fdot2(a, b, c, false);
#else
    return c + (float)a[0] * (float)b[0] + (float)a[1] * (float)b[1];
#endif
}

// One wave (64 threads) == one batch element. No __syncthreads anywhere:
// all LDS dependencies are same-wave (lgkmcnt-ordered).
__launch_bounds__(64, 2)
__global__ void afm_kernel(const int* __restrict__ features,
                           const float* __restrict__ emb_table,
                           const float* __restrict__ coeff_table,
                           const float* __restrict__ bias,
                           const float* __restrict__ att_w,
                           const float* __restrict__ att_b,
                           const float* __restrict__ pvec,
                           const float* __restrict__ wvec,
                           float* __restrict__ out)
{
    // chunk-major: chunk qc = h*4 + c holds logical dims d = c*16 + h*8 + [0..8)
    __shared__ __align__(16) unsigned short emb3[8][NFPAD][8];

    const int b    = blockIdx.x;
    const int lane = threadIdx.x;   // 0..63
    const int col  = lane & 31;     // MFMA output col = pair within tile
    const int h    = lane >> 5;     // k-half
    const int h4   = h * 4;

    // ---- earliest: random feature load, then dependent coeff load ----
    int myfeat = 0;
    if (lane < NFIELDS) myfeat = features[b * NFIELDS + lane];
    float cacc = 0.f;
    if (lane < NFIELDS)       cacc = coeff_table[myfeat];
    else if (lane == NFIELDS) cacc = bias[0];

    // ---- per-lane register weights (A-operand = att_w, stationary) ----
    f16x8 afragW[4];
    f16x2 w2[16];
    #pragma unroll
    for (int c = 0; c < 4; ++c) {
        const int d0 = c * 16 + h * 8;
        const float4 wa0 = *reinterpret_cast<const float4*>(&att_w[col * EMBD + d0]);
        const float4 wa1 = *reinterpret_cast<const float4*>(&att_w[col * EMBD + d0 + 4]);
        F16x8U bf;
        bf.v[0] = (_Float16)wa0.x; bf.v[1] = (_Float16)wa0.y;
        bf.v[2] = (_Float16)wa0.z; bf.v[3] = (_Float16)wa0.w;
        bf.v[4] = (_Float16)wa1.x; bf.v[5] = (_Float16)wa1.y;
        bf.v[6] = (_Float16)wa1.z; bf.v[7] = (_Float16)wa1.w;
        afragW[c] = bf.v;
        const float4 wv0 = *reinterpret_cast<const float4*>(&wvec[d0]);
        const float4 wv1 = *reinterpret_cast<const float4*>(&wvec[d0 + 4]);
        f16x2 t0; t0[0] = (_Float16)wv0.x; t0[1] = (_Float16)wv0.y; w2[c * 4 + 0] = t0;
        f16x2 t1; t1[0] = (_Float16)wv0.z; t1[1] = (_Float16)wv0.w; w2[c * 4 + 1] = t1;
        f16x2 t2; t2[0] = (_Float16)wv1.x; t2[1] = (_Float16)wv1.y; w2[c * 4 + 2] = t2;
        f16x2 t3; t3[0] = (_Float16)wv1.z; t3[1] = (_Float16)wv1.w; w2[c * 4 + 3] = t3;
    }
    // per-reg output-row constants: row(reg) = (reg&3) + 8*(reg>>2) + 4*h
    float attb_r[16], p_r[16];
    #pragma unroll
    for (int reg = 0; reg < 16; ++reg) {
        const int r = (reg & 3) + 8 * (reg >> 2) + 4 * h;
        attb_r[reg] = att_b[r];
        p_r[reg]    = pvec[r];
    }

    // ---- gather embeddings -> f16 chunk-major LDS (same-wave, no barrier) ----
    #pragma unroll
    for (int k = 0; k < 13; ++k) {
        const int idx = lane + k * 64;
        if (idx < NFIELDS * 16) {
            const int f  = idx >> 4;
            const int d0 = (idx & 15) * 4;
            const int ff = __shfl(myfeat, f, 64);   // lane f holds features[b,f]
            const float4 v = *reinterpret_cast<const float4*>(
                &emb_table[(size_t)ff * EMBD + d0]);
            const int c  = d0 >> 4;
            const int hh = (d0 >> 3) & 1;
            const int e0 = d0 & 7;                  // 0 or 4
            U32F t0, t1;
            t0.h[0] = (_Float16)v.x; t0.h[1] = (_Float16)v.y;
            t1.h[0] = (_Float16)v.z; t1.h[1] = (_Float16)v.w;
            uint2 pk; pk.x = t0.u; pk.y = t1.u;
            *reinterpret_cast<uint2*>(&emb3[hh * 4 + c][f][e0]) = pk;
        }
    }
    __builtin_amdgcn_wave_barrier();   // compile-time order pin (no HW cost)

    // ---- main: 39 tiles of 32 pairs, closed-form (i,j), online softmax ----
    const unsigned short* const ebase = &emb3[0][0][0] + h4 * CHSTR;
    float m_run = MNEG, s_run = 0.f, st_run = 0.f;

    #pragma unroll 2
    for (int tile = 0; tile < NTILES; ++tile) {
        const int q  = tile * 32 + col;
        const int qc = (q < NPAIRS) ? q : (NPAIRS - 1);
        // exact triangular inverse: 9801-8*off(i) = (99-2i)^2
        const float sq = sqrtf((float)(9801 - 8 * qc));
        const int i   = (int)((99.0f - sq) * 0.5f);
        const int off = i * NFIELDS - ((i * (i + 1)) >> 1);
        const int j   = i + 1 + (qc - off);

        const unsigned short* pi = ebase + i * 8;
        const unsigned short* pj = ebase + j * 8;

        f32x16 acc;
        #pragma unroll
        for (int reg = 0; reg < 16; ++reg) acc[reg] = attb_r[reg];  // bias in acc

        float t_half = 0.f;
        #pragma unroll
        for (int c = 0; c < 4; ++c) {
            F16x8U ai, aj;
            ai.q = *reinterpret_cast<const uint4*>(pi + c * CHSTR);
            aj.q = *reinterpret_cast<const uint4*>(pj + c * CHSTR);
            const f16x2 x0 = ai.h2[0] * aj.h2[0];   // v_pk_mul_f16
            const f16x2 x1 = ai.h2[1] * aj.h2[1];
            const f16x2 x2 = ai.h2[2] * aj.h2[2];
            const f16x2 x3 = ai.h2[3] * aj.h2[3];
            t_half = dot2acc(x0, w2[c * 4 + 0], t_half);
            t_half = dot2acc(x1, w2[c * 4 + 1], t_half);
            t_half = dot2acc(x2, w2[c * 4 + 2], t_half);
            t_half = dot2acc(x3, w2[c * 4 + 3], t_half);
            F16x8U bf;
            bf.h2[0] = x0; bf.h2[1] = x1; bf.h2[2] = x2; bf.h2[3] = x3;
            acc = __builtin_amdgcn_mfma_f32_32x32x16_f16(afragW[c], bf.v, acc, 0, 0, 0);
        }

        // epilogue: relu·p over the 16 in-register rows
        float sp = 0.f;
        #pragma unroll
        for (int reg = 0; reg < 16; ++reg)
            sp = fmaf(fmaxf(acc[reg], 0.f), p_r[reg], sp);

        // one packed cross-half exchange for (sp, t_half)
        U32F pkd; pkd.h = pkrtz(sp, t_half);
        U32F oth; oth.u = (unsigned int)__shfl_xor((int)pkd.u, 32, 64);
        const float sc = sp + (float)oth.h[0];
        const float tf = t_half + (float)oth.h[1];

        // online softmax update (h=0/h=1 duplicates cancel in ST/S)
        const bool valid = (q < NPAIRS);
        const float scm = valid ? sc : MNEG;
        const float mn  = fmaxf(m_run, scm);
        const float scale = __expf(m_run - mn);
        const float e     = valid ? __expf(sc - mn) : 0.f;
        s_run  = s_run  * scale + e;
        st_run = st_run * scale + e * tf;
        m_run  = mn;
    }

    // ---- wave-internal butterfly: softmax state + coeff/bias sum ----
    #pragma unroll
    for (int m = 1; m < 64; m <<= 1) {
        const float m2  = __shfl_xor(m_run, m, 64);
        const float s2  = __shfl_xor(s_run, m, 64);
        const float st2 = __shfl_xor(st_run, m, 64);
        cacc += __shfl_xor(cacc, m, 64);
        const float mn  = fmaxf(m_run, m2);
        const float ea  = __expf(m_run - mn);
        const float eb  = __expf(m2 - mn);
        s_run  = s_run * ea + s2 * eb;
        st_run = st_run * ea + st2 * eb;
        m_run  = mn;
    }

    if (lane == 0) out[b] = st_run / s_run + cacc;
}

extern "C" void kernel_launch(void* const* d_in, const int* in_sizes, int n_in,
                              void* d_out, int out_size, void* d_ws, size_t ws_size,
                              hipStream_t stream) {
    const int*   features    = (const int*)d_in[0];
    const float* emb_table   = (const float*)d_in[1];
    const float* coeff_table = (const float*)d_in[2];
    const float* bias        = (const float*)d_in[3];
    const float* att_w       = (const float*)d_in[4];
    const float* att_b       = (const float*)d_in[5];
    const float* pvec        = (const float*)d_in[6];
    const float* wvec        = (const float*)d_in[7];
    float* out = (float*)d_out;

    const int batch = in_sizes[0] / NFIELDS;   // 2048
    afm_kernel<<<batch, 64, 0, stream>>>(
        features, emb_table, coeff_table, bias, att_w, att_b, pvec, wvec, out);
}